// Round 12
// baseline (199.164 us; speedup 1.0000x reference)
//
#include <hip/hip_runtime.h>

#define NB  32
#define NLQ 64
#define NLV 128
#define NQS 512
#define NFS 1024
#define NBN 512
#define CC  2.8853900817779268f   // 2*log2(e):  exp(2x) = exp2(CC*x)

typedef float  floatx4 __attribute__((ext_vector_type(4)));
typedef __bf16 bf16x8  __attribute__((ext_vector_type(8)));
typedef unsigned short us;

__device__ __forceinline__ us f2bf(float f) {
    unsigned int u = __float_as_uint(f);
    u += 0x7fffu + ((u >> 16) & 1u);   // round-to-nearest-even
    return (us)(u >> 16);
}
// truncating pack of two fp32 -> packed bf16x2, one v_perm_b32
__device__ __forceinline__ unsigned int pktrunc(float lo, float hi) {
    return __builtin_amdgcn_perm(__float_as_uint(hi), __float_as_uint(lo), 0x07060302u);
}
__device__ __forceinline__ float blo(unsigned int u) {
    return __uint_as_float(u << 16);
}
__device__ __forceinline__ float bhi(unsigned int u) {
    return __uint_as_float(u & 0xffff0000u);
}

// ---------------- convert: fp32 -> bf16 (phr,vis,W,U); also writes sgf[:, :512]=phr
#define PHR4 262144
#define VIS4 1048576
#define WW4  65536
#define UU4  131072
#define TOT4 (PHR4 + VIS4 + WW4 + UU4)   // 1,507,328 float4s

__global__ __launch_bounds__(256) void convert_bf16(
    const float* __restrict__ phr, const float* __restrict__ vis,
    const float* __restrict__ W,   const float* __restrict__ U,
    us* __restrict__ phr_b, us* __restrict__ vis_b,
    us* __restrict__ W_b,   us* __restrict__ U_b,
    float* __restrict__ out_sgf)
{
    int i = blockIdx.x * 256 + threadIdx.x;
    if (i >= TOT4) return;
    const float* src; us* dst; int o;
    if (i < PHR4)              { src = phr; dst = phr_b; o = i; }
    else if (i < PHR4 + VIS4)  { src = vis; dst = vis_b; o = i - PHR4; }
    else if (i < PHR4 + VIS4 + WW4) { src = W; dst = W_b; o = i - PHR4 - VIS4; }
    else                       { src = U; dst = U_b; o = i - PHR4 - VIS4 - WW4; }
    float4 v = ((const float4*)src)[o];
    uint2 r = { pktrunc(v.x, v.y), pktrunc(v.z, v.w) };
    *(uint2*)(dst + (size_t)o * 4) = r;
    if (i < PHR4) {   // concat left half: sgf[row, 0:512] = phr (fp32, exact)
        int row = o >> 7, c4 = o & 127;
        ((float4*)out_sgf)[(size_t)row * 384 + c4] = v;
    }
}

// ---------------- GEMM: 64x64 tile, K-tile 32, bf16 in, 4 waves -------------
// Epilogue: Y = exp2(CC*(acc[+bias])) stored bf16 (tanh product trick).
__device__ __forceinline__ void gemm64(
    us* As, us* Bs,                       // [64*40] each
    const us* __restrict__ A, const us* __restrict__ Bt,
    const float* __restrict__ bias, us* __restrict__ C,
    int K, int bx, int by, int hasb)
{
    const int tid  = threadIdx.x;
    const int m0   = bx * 64;
    const int n0   = by * 64;
    const int wave = tid >> 6;
    const int lane = tid & 63;
    const int wm   = (wave >> 1) * 32;
    const int wn   = (wave & 1) * 32;
    const int srow = tid >> 2;          // 0..63
    const int sk   = (tid & 3) * 8;     // k offset (elements): 0,8,16,24
    const int fm   = lane & 15;
    const int fko  = (lane >> 4) * 8;

    floatx4 acc[2][2] = {};
    const us* ag = A  + (size_t)(m0 + srow) * K + sk;
    const us* bg = Bt + (size_t)(n0 + srow) * K + sk;

    uint4 av = *(const uint4*)(ag);
    uint4 bv = *(const uint4*)(bg);

    for (int k0 = 0; k0 < K; k0 += 32) {
        __syncthreads();
        *(uint4*)(As + srow * 40 + sk) = av;
        *(uint4*)(Bs + srow * 40 + sk) = bv;
        const int kn = k0 + 32;
        if (kn < K) {                   // next-tile load; hidden by other blocks
            av = *(const uint4*)(ag + kn);
            bv = *(const uint4*)(bg + kn);
        }
        __syncthreads();
        bf16x8 am[2], bn[2];
        #pragma unroll
        for (int i = 0; i < 2; ++i)
            am[i] = *(const bf16x8*)(As + (wm + 16 * i + fm) * 40 + fko);
        #pragma unroll
        for (int j = 0; j < 2; ++j)
            bn[j] = *(const bf16x8*)(Bs + (wn + 16 * j + fm) * 40 + fko);
        #pragma unroll
        for (int i = 0; i < 2; ++i)
            #pragma unroll
            for (int j = 0; j < 2; ++j)
                acc[i][j] = __builtin_amdgcn_mfma_f32_16x16x32_bf16(am[i], bn[j], acc[i][j], 0, 0, 0);
    }

    // C/D layout: col = lane&15, row = (lane>>4)*4 + reg
    const int cr = (lane >> 4) * 4;
    const int cc = lane & 15;
    #pragma unroll
    for (int i = 0; i < 2; ++i)
        #pragma unroll
        for (int j = 0; j < 2; ++j)
            #pragma unroll
            for (int r = 0; r < 4; ++r) {
                int gm = m0 + wm + 16 * i + cr + r;
                int gn = n0 + wn + 16 * j + cc;
                float v = acc[i][j][r];
                if (hasb) v += bias[gn];
                C[(size_t)gm * NBN + gn] = f2bf(__builtin_amdgcn_exp2f(CC * v));
            }
}

// blocks 0..255: Yq=exp2(CC*(phr@W^T+b)) (M=2048,K=512, nbx=32)
// blocks 256..767: Yv=exp2(CC*(vis@U^T)) (M=4096,K=1024, nbx=64)
__global__ __launch_bounds__(256) void gemm_both(
    const us* __restrict__ phr_b, const us* __restrict__ W_b,
    const float* __restrict__ bias,
    const us* __restrict__ vis_b, const us* __restrict__ U_b,
    us* __restrict__ whY, us* __restrict__ uvY)
{
    __shared__ __align__(16) us As[64 * 40];
    __shared__ __align__(16) us Bs[64 * 40];
    int blk = blockIdx.x;
    if (blk < 256) {
        gemm64(As, Bs, phr_b, W_b, bias, whY, NQS, blk % 32, blk / 32, 1);
    } else {
        blk -= 256;
        gemm64(As, Bs, vis_b, U_b, bias, uvY, NFS, blk % 64, blk / 64, 0);
    }
}

// ---------------- energies + softmax ---------------------------------------
// blk = q*32 + b.  tanh(x) = 1 - 2/(1 + Yq[n]*Yv[n]).
// Lane mapping: nl = lane&15 owns n in [nl*32, nl*32+32); vl = lane>>4 picks v.
// NOTE: launched 3x this round (idempotent) to measure T_energize = (dur - base)/2.
__global__ __launch_bounds__(256) void energize(
    const us* __restrict__ whY,   // [2048,512] bf16
    const us* __restrict__ uvY,   // [4096,512] bf16
    const float* __restrict__ wvec,
    float* __restrict__ out_w, float* __restrict__ out_e)
{
    const float LOG2E = 1.4426950408889634f;
    const int blk  = blockIdx.x;
    const int q    = blk >> 5;
    const int b    = blk & 31;
    const int row  = b * NLQ + q;
    const int tid  = threadIdx.x;
    const int wave = tid >> 6;
    const int lane = tid & 63;
    const int nl   = lane & 15;
    const int vl   = lane >> 4;
    const int n0   = nl << 5;          // 32 n per lane

    __shared__ float e_s[128];

    // per-lane constants: Yq[32], w[32] in registers
    float Yq[32], w[32];
    {
        const us* yqp = whY + (size_t)row * NBN + n0;
        #pragma unroll
        for (int i = 0; i < 4; ++i) {
            uint4 t = *(const uint4*)(yqp + i * 8);
            Yq[i*8+0]=blo(t.x); Yq[i*8+1]=bhi(t.x);
            Yq[i*8+2]=blo(t.y); Yq[i*8+3]=bhi(t.y);
            Yq[i*8+4]=blo(t.z); Yq[i*8+5]=bhi(t.z);
            Yq[i*8+6]=blo(t.w); Yq[i*8+7]=bhi(t.w);
        }
        #pragma unroll
        for (int i = 0; i < 8; ++i) {
            float4 t = *(const float4*)(wvec + n0 + i * 4);
            w[i*4+0]=t.x; w[i*4+1]=t.y; w[i*4+2]=t.z; w[i*4+3]=t.w;
        }
    }
    float sumw = 0.f;
    #pragma unroll
    for (int i = 0; i < 32; ++i) sumw += w[i];
    #pragma unroll
    for (int m = 1; m <= 8; m <<= 1) sumw += __shfl_xor(sumw, m);

    // e_v = sumw - 2 * sum_n w_n / (1 + Yq[n]*Yv[n])
    #pragma unroll 2
    for (int pass = 0; pass < 8; ++pass) {
        const int v = wave * 32 + pass * 4 + vl;
        const us* uvp = uvY + ((size_t)b * NLV + v) * NBN + n0;
        float s0 = 0.f, s1 = 0.f;
        #pragma unroll
        for (int i = 0; i < 4; ++i) {
            uint4 t = *(const uint4*)(uvp + i * 8);
            const int k = i * 8;
            float d0 = fmaf(blo(t.x), Yq[k+0], 1.f);
            float d1 = fmaf(bhi(t.x), Yq[k+1], 1.f);
            float d2 = fmaf(blo(t.y), Yq[k+2], 1.f);
            float d3 = fmaf(bhi(t.y), Yq[k+3], 1.f);
            float d4 = fmaf(blo(t.z), Yq[k+4], 1.f);
            float d5 = fmaf(bhi(t.z), Yq[k+5], 1.f);
            float d6 = fmaf(blo(t.w), Yq[k+6], 1.f);
            float d7 = fmaf(bhi(t.w), Yq[k+7], 1.f);
            s0 = fmaf(w[k+0], __builtin_amdgcn_rcpf(d0), s0);
            s1 = fmaf(w[k+1], __builtin_amdgcn_rcpf(d1), s1);
            s0 = fmaf(w[k+2], __builtin_amdgcn_rcpf(d2), s0);
            s1 = fmaf(w[k+3], __builtin_amdgcn_rcpf(d3), s1);
            s0 = fmaf(w[k+4], __builtin_amdgcn_rcpf(d4), s0);
            s1 = fmaf(w[k+5], __builtin_amdgcn_rcpf(d5), s1);
            s0 = fmaf(w[k+6], __builtin_amdgcn_rcpf(d6), s0);
            s1 = fmaf(w[k+7], __builtin_amdgcn_rcpf(d7), s1);
        }
        float s = s0 + s1;
        #pragma unroll
        for (int m = 1; m <= 8; m <<= 1) s += __shfl_xor(s, m);
        if (nl == 0) e_s[v] = fmaf(-2.f, s, sumw);
    }
    __syncthreads();

    if (wave == 0) {
        float e0 = e_s[lane];
        float e1 = e_s[lane + 64];
        float m = fmaxf(e0, e1);
        #pragma unroll
        for (int off = 32; off; off >>= 1) m = fmaxf(m, __shfl_xor(m, off));
        float x0 = __builtin_amdgcn_exp2f((e0 - m) * LOG2E);
        float x1 = __builtin_amdgcn_exp2f((e1 - m) * LOG2E);
        float ss = x0 + x1;
        #pragma unroll
        for (int off = 32; off; off >>= 1) ss += __shfl_xor(ss, off);
        float inv = __builtin_amdgcn_rcpf(ss);
        float p0 = x0 * inv, p1 = x1 * inv;
        size_t o = (size_t)row * NLV;
        out_w[o + lane]      = p0;
        out_w[o + lane + 64] = p1;
        out_e[o + lane]      = e0;
        out_e[o + lane + 64] = e1;
    }
}

// ---------------- aligned (bf16 vis; p read from out_w) ---------------------
// blk = qg*32 + b (qg: group of 4 q). Thread owns 4 f for 4 q.
__global__ __launch_bounds__(256) void aligned_k(
    const us* __restrict__ vis_b,     // [32,128,1024] bf16
    const float* __restrict__ p_w,    // [2048,128] fp32 (= out_w)
    float* __restrict__ out_sgf)      // [32,64,1536]
{
    const int blk = blockIdx.x;
    const int b   = blk & 31;
    const int qg  = blk >> 5;         // 0..15
    const int tid = threadIdx.x;

    __shared__ float p_s[4][128];
    if (tid < 128) {
        const float* src = p_w + (size_t)(b * NLQ + qg * 4) * NLV;
        ((float4*)&p_s[0][0])[tid] = ((const float4*)src)[tid];
    }
    __syncthreads();

    const int f0 = tid * 4;
    float4 acc[4] = {};
    const us* vb = vis_b + (size_t)b * NLV * NFS + f0;
    for (int v0 = 0; v0 < NLV; v0 += 4) {
        float4 pv[4];
        #pragma unroll
        for (int qq = 0; qq < 4; ++qq) pv[qq] = *(const float4*)&p_s[qq][v0];
        #pragma unroll
        for (int dv = 0; dv < 4; ++dv) {
            uint2 u = *(const uint2*)(vb + (size_t)(v0 + dv) * NFS);
            float x0 = blo(u.x), x1 = bhi(u.x), x2 = blo(u.y), x3 = bhi(u.y);
            #pragma unroll
            for (int qq = 0; qq < 4; ++qq) {
                float p = (dv == 0) ? pv[qq].x : (dv == 1) ? pv[qq].y
                        : (dv == 2) ? pv[qq].z : pv[qq].w;
                acc[qq].x = fmaf(p, x0, acc[qq].x);
                acc[qq].y = fmaf(p, x1, acc[qq].y);
                acc[qq].z = fmaf(p, x2, acc[qq].z);
                acc[qq].w = fmaf(p, x3, acc[qq].w);
            }
        }
    }
    #pragma unroll
    for (int qq = 0; qq < 4; ++qq) {
        size_t row = (size_t)(b * NLQ + qg * 4 + qq);
        *(float4*)(out_sgf + row * (NQS + NFS) + NQS + f0) = acc[qq];
    }
}

extern "C" void kernel_launch(void* const* d_in, const int* in_sizes, int n_in,
                              void* d_out, int out_size, void* d_ws, size_t ws_size,
                              hipStream_t stream) {
    const float* phr  = (const float*)d_in[0];
    const float* vis  = (const float*)d_in[1];
    const float* W    = (const float*)d_in[2];
    const float* U    = (const float*)d_in[3];
    const float* bias = (const float*)d_in[4];
    const float* wvec = (const float*)d_in[5];

    char* ws = (char*)d_ws;
    us* phr_b = (us*)ws;                                  // 2 MB
    us* vis_b = (us*)(ws + (2u << 20));                   // 8 MB
    us* W_b   = (us*)(ws + (10u << 20));                  // 0.5 MB
    us* U_b   = (us*)(ws + (10u << 20) + (512u << 10));   // 1 MB
    us* whY   = (us*)(ws + (12u << 20));                  // 2 MB
    us* uvY   = (us*)(ws + (14u << 20));                  // 4 MB

    float* out     = (float*)d_out;
    float* out_sgf = out;
    float* out_w   = out_sgf + (size_t)NB * NLQ * (NQS + NFS);
    float* out_e   = out_w   + (size_t)NB * NLQ * NLV;

    convert_bf16<<<(TOT4 + 255) / 256, 256, 0, stream>>>(
        phr, vis, W, U, phr_b, vis_b, W_b, U_b, out_sgf);
    gemm_both<<<768, 256, 0, stream>>>(phr_b, W_b, bias, vis_b, U_b, whY, uvY);
    // Launched 3x (idempotent) — measurement round: T_energize = (dur - base)/2
    energize<<<NB * NLQ, 256, 0, stream>>>(whY, uvY, wvec, out_w, out_e);
    energize<<<NB * NLQ, 256, 0, stream>>>(whY, uvY, wvec, out_w, out_e);
    energize<<<NB * NLQ, 256, 0, stream>>>(whY, uvY, wvec, out_w, out_e);
    aligned_k<<<NB * 16, 256, 0, stream>>>(vis_b, out_w, out_sgf);
}

// Round 13
// 134.134 us; speedup vs baseline: 1.4848x; 1.4848x over previous
//
#include <hip/hip_runtime.h>

#define NB  32
#define NLQ 64
#define NLV 128
#define NQS 512
#define NFS 1024
#define NBN 512
#define CC  2.8853900817779268f   // 2*log2(e):  exp(2x) = exp2(CC*x)

typedef float  floatx4 __attribute__((ext_vector_type(4)));
typedef __bf16 bf16x8  __attribute__((ext_vector_type(8)));
typedef unsigned short us;

__device__ __forceinline__ us f2bf(float f) {
    unsigned int u = __float_as_uint(f);
    u += 0x7fffu + ((u >> 16) & 1u);   // round-to-nearest-even
    return (us)(u >> 16);
}
// truncating pack of two fp32 -> packed bf16x2, one v_perm_b32
__device__ __forceinline__ unsigned int pktrunc(float lo, float hi) {
    return __builtin_amdgcn_perm(__float_as_uint(hi), __float_as_uint(lo), 0x07060302u);
}
__device__ __forceinline__ float blo(unsigned int u) {
    return __uint_as_float(u << 16);
}
__device__ __forceinline__ float bhi(unsigned int u) {
    return __uint_as_float(u & 0xffff0000u);
}

// ---------------- convert: fp32 -> bf16 (phr,vis,W,U); also writes sgf[:, :512]=phr
#define PHR4 262144
#define VIS4 1048576
#define WW4  65536
#define UU4  131072
#define TOT4 (PHR4 + VIS4 + WW4 + UU4)   // 1,507,328 float4s

__global__ __launch_bounds__(256) void convert_bf16(
    const float* __restrict__ phr, const float* __restrict__ vis,
    const float* __restrict__ W,   const float* __restrict__ U,
    us* __restrict__ phr_b, us* __restrict__ vis_b,
    us* __restrict__ W_b,   us* __restrict__ U_b,
    float* __restrict__ out_sgf)
{
    int i = blockIdx.x * 256 + threadIdx.x;
    if (i >= TOT4) return;
    const float* src; us* dst; int o;
    if (i < PHR4)              { src = phr; dst = phr_b; o = i; }
    else if (i < PHR4 + VIS4)  { src = vis; dst = vis_b; o = i - PHR4; }
    else if (i < PHR4 + VIS4 + WW4) { src = W; dst = W_b; o = i - PHR4 - VIS4; }
    else                       { src = U; dst = U_b; o = i - PHR4 - VIS4 - WW4; }
    float4 v = ((const float4*)src)[o];
    uint2 r = { pktrunc(v.x, v.y), pktrunc(v.z, v.w) };
    *(uint2*)(dst + (size_t)o * 4) = r;
    if (i < PHR4) {   // concat left half: sgf[row, 0:512] = phr (fp32, exact)
        int row = o >> 7, c4 = o & 127;
        ((float4*)out_sgf)[(size_t)row * 384 + c4] = v;
    }
}

// ---------------- GEMM: 64x64 tile, K-tile 32, bf16 in, 4 waves -------------
// Epilogue: Y = exp2(CC*(acc[+bias])) stored bf16 (tanh product trick).
__device__ __forceinline__ void gemm64(
    us* As, us* Bs,                       // [64*40] each
    const us* __restrict__ A, const us* __restrict__ Bt,
    const float* __restrict__ bias, us* __restrict__ C,
    int K, int bx, int by, int hasb)
{
    const int tid  = threadIdx.x;
    const int m0   = bx * 64;
    const int n0   = by * 64;
    const int wave = tid >> 6;
    const int lane = tid & 63;
    const int wm   = (wave >> 1) * 32;
    const int wn   = (wave & 1) * 32;
    const int srow = tid >> 2;          // 0..63
    const int sk   = (tid & 3) * 8;     // k offset (elements): 0,8,16,24
    const int fm   = lane & 15;
    const int fko  = (lane >> 4) * 8;

    floatx4 acc[2][2] = {};
    const us* ag = A  + (size_t)(m0 + srow) * K + sk;
    const us* bg = Bt + (size_t)(n0 + srow) * K + sk;

    uint4 av = *(const uint4*)(ag);
    uint4 bv = *(const uint4*)(bg);

    for (int k0 = 0; k0 < K; k0 += 32) {
        __syncthreads();
        *(uint4*)(As + srow * 40 + sk) = av;
        *(uint4*)(Bs + srow * 40 + sk) = bv;
        const int kn = k0 + 32;
        if (kn < K) {                   // next-tile load; hidden by other blocks
            av = *(const uint4*)(ag + kn);
            bv = *(const uint4*)(bg + kn);
        }
        __syncthreads();
        bf16x8 am[2], bn[2];
        #pragma unroll
        for (int i = 0; i < 2; ++i)
            am[i] = *(const bf16x8*)(As + (wm + 16 * i + fm) * 40 + fko);
        #pragma unroll
        for (int j = 0; j < 2; ++j)
            bn[j] = *(const bf16x8*)(Bs + (wn + 16 * j + fm) * 40 + fko);
        #pragma unroll
        for (int i = 0; i < 2; ++i)
            #pragma unroll
            for (int j = 0; j < 2; ++j)
                acc[i][j] = __builtin_amdgcn_mfma_f32_16x16x32_bf16(am[i], bn[j], acc[i][j], 0, 0, 0);
    }

    // C/D layout: col = lane&15, row = (lane>>4)*4 + reg
    const int cr = (lane >> 4) * 4;
    const int cc = lane & 15;
    #pragma unroll
    for (int i = 0; i < 2; ++i)
        #pragma unroll
        for (int j = 0; j < 2; ++j)
            #pragma unroll
            for (int r = 0; r < 4; ++r) {
                int gm = m0 + wm + 16 * i + cr + r;
                int gn = n0 + wn + 16 * j + cc;
                float v = acc[i][j][r];
                if (hasb) v += bias[gn];
                C[(size_t)gm * NBN + gn] = f2bf(__builtin_amdgcn_exp2f(CC * v));
            }
}

// blocks 0..255: Yq=exp2(CC*(phr@W^T+b)) (M=2048,K=512, nbx=32)
// blocks 256..767: Yv=exp2(CC*(vis@U^T)) (M=4096,K=1024, nbx=64)
__global__ __launch_bounds__(256) void gemm_both(
    const us* __restrict__ phr_b, const us* __restrict__ W_b,
    const float* __restrict__ bias,
    const us* __restrict__ vis_b, const us* __restrict__ U_b,
    us* __restrict__ whY, us* __restrict__ uvY)
{
    __shared__ __align__(16) us As[64 * 40];
    __shared__ __align__(16) us Bs[64 * 40];
    int blk = blockIdx.x;
    if (blk < 256) {
        gemm64(As, Bs, phr_b, W_b, bias, whY, NQS, blk % 32, blk / 32, 1);
    } else {
        blk -= 256;
        gemm64(As, Bs, vis_b, U_b, bias, uvY, NFS, blk % 64, blk / 64, 0);
    }
}

// ---------------- energies + softmax, 2 q per block -------------------------
// blk = qp*32 + b; q = qp*2 + {0,1}.  tanh(x) = 1 - 2/(1 + Yq[n]*Yv[n]).
// Lane: nl = lane&15 owns n in [nl*32, nl*32+32); vl = lane>>4 picks v.
// Yv loaded+unpacked ONCE, used for both q.  Next-pass loads prefetched.
__global__ __launch_bounds__(256) void energize(
    const us* __restrict__ whY,   // [2048,512] bf16
    const us* __restrict__ uvY,   // [4096,512] bf16
    const float* __restrict__ wvec,
    float* __restrict__ out_w, float* __restrict__ out_e)
{
    const float LOG2E = 1.4426950408889634f;
    const int blk  = blockIdx.x;
    const int qp   = blk >> 5;
    const int b    = blk & 31;
    const int row0 = b * NLQ + qp * 2;   // q0 row; q1 = row0+1
    const int tid  = threadIdx.x;
    const int wave = tid >> 6;
    const int lane = tid & 63;
    const int nl   = lane & 15;
    const int vl   = lane >> 4;
    const int n0   = nl << 5;            // 32 n per lane

    __shared__ float e_s[2][128];

    // per-lane constants: w[32], Yq0[32], Yq1[32]
    float w[32], Yq0[32], Yq1[32];
    #pragma unroll
    for (int i = 0; i < 8; ++i) {
        float4 t = *(const float4*)(wvec + n0 + i * 4);
        w[i*4+0]=t.x; w[i*4+1]=t.y; w[i*4+2]=t.z; w[i*4+3]=t.w;
    }
    #pragma unroll
    for (int i = 0; i < 4; ++i) {
        uint4 t0 = *(const uint4*)(whY + (size_t)row0 * NBN + n0 + i * 8);
        uint4 t1 = *(const uint4*)(whY + (size_t)(row0 + 1) * NBN + n0 + i * 8);
        const int k = i * 8;
        Yq0[k+0]=blo(t0.x); Yq0[k+1]=bhi(t0.x); Yq0[k+2]=blo(t0.y); Yq0[k+3]=bhi(t0.y);
        Yq0[k+4]=blo(t0.z); Yq0[k+5]=bhi(t0.z); Yq0[k+6]=blo(t0.w); Yq0[k+7]=bhi(t0.w);
        Yq1[k+0]=blo(t1.x); Yq1[k+1]=bhi(t1.x); Yq1[k+2]=blo(t1.y); Yq1[k+3]=bhi(t1.y);
        Yq1[k+4]=blo(t1.z); Yq1[k+5]=bhi(t1.z); Yq1[k+6]=blo(t1.w); Yq1[k+7]=bhi(t1.w);
    }
    float sumw = 0.f;
    #pragma unroll
    for (int i = 0; i < 32; ++i) sumw += w[i];
    #pragma unroll
    for (int m = 1; m <= 8; m <<= 1) sumw += __shfl_xor(sumw, m);

    const us* uvbase = uvY + ((size_t)b * NLV + wave * 32) * NBN + n0;

    uint4 t[4];
    #pragma unroll
    for (int i = 0; i < 4; ++i)
        t[i] = *(const uint4*)(uvbase + (size_t)vl * NBN + i * 8);

    // e_v = sumw - 2 * sum_n w_n / (1 + Yq[n]*Yv[n])
    #pragma unroll
    for (int pass = 0; pass < 8; ++pass) {
        uint4 cur[4] = { t[0], t[1], t[2], t[3] };
        if (pass < 7) {
            const us* up = uvbase + (size_t)((pass + 1) * 4 + vl) * NBN;
            #pragma unroll
            for (int i = 0; i < 4; ++i) t[i] = *(const uint4*)(up + i * 8);
        }
        float sA0 = 0.f, sA1 = 0.f, sB0 = 0.f, sB1 = 0.f;
        #pragma unroll
        for (int i = 0; i < 4; ++i) {
            const int k = i * 8;
            unsigned int ux = cur[i].x, uy = cur[i].y, uz = cur[i].z, uw = cur[i].w;
            float yv0 = blo(ux), yv1 = bhi(ux), yv2 = blo(uy), yv3 = bhi(uy);
            float yv4 = blo(uz), yv5 = bhi(uz), yv6 = blo(uw), yv7 = bhi(uw);
            float dA0 = fmaf(yv0, Yq0[k+0], 1.f), dB0 = fmaf(yv0, Yq1[k+0], 1.f);
            float dA1 = fmaf(yv1, Yq0[k+1], 1.f), dB1 = fmaf(yv1, Yq1[k+1], 1.f);
            float dA2 = fmaf(yv2, Yq0[k+2], 1.f), dB2 = fmaf(yv2, Yq1[k+2], 1.f);
            float dA3 = fmaf(yv3, Yq0[k+3], 1.f), dB3 = fmaf(yv3, Yq1[k+3], 1.f);
            float dA4 = fmaf(yv4, Yq0[k+4], 1.f), dB4 = fmaf(yv4, Yq1[k+4], 1.f);
            float dA5 = fmaf(yv5, Yq0[k+5], 1.f), dB5 = fmaf(yv5, Yq1[k+5], 1.f);
            float dA6 = fmaf(yv6, Yq0[k+6], 1.f), dB6 = fmaf(yv6, Yq1[k+6], 1.f);
            float dA7 = fmaf(yv7, Yq0[k+7], 1.f), dB7 = fmaf(yv7, Yq1[k+7], 1.f);
            sA0 = fmaf(w[k+0], __builtin_amdgcn_rcpf(dA0), sA0);
            sB0 = fmaf(w[k+0], __builtin_amdgcn_rcpf(dB0), sB0);
            sA1 = fmaf(w[k+1], __builtin_amdgcn_rcpf(dA1), sA1);
            sB1 = fmaf(w[k+1], __builtin_amdgcn_rcpf(dB1), sB1);
            sA0 = fmaf(w[k+2], __builtin_amdgcn_rcpf(dA2), sA0);
            sB0 = fmaf(w[k+2], __builtin_amdgcn_rcpf(dB2), sB0);
            sA1 = fmaf(w[k+3], __builtin_amdgcn_rcpf(dA3), sA1);
            sB1 = fmaf(w[k+3], __builtin_amdgcn_rcpf(dB3), sB1);
            sA0 = fmaf(w[k+4], __builtin_amdgcn_rcpf(dA4), sA0);
            sB0 = fmaf(w[k+4], __builtin_amdgcn_rcpf(dB4), sB0);
            sA1 = fmaf(w[k+5], __builtin_amdgcn_rcpf(dA5), sA1);
            sB1 = fmaf(w[k+5], __builtin_amdgcn_rcpf(dB5), sB1);
            sA0 = fmaf(w[k+6], __builtin_amdgcn_rcpf(dA6), sA0);
            sB0 = fmaf(w[k+6], __builtin_amdgcn_rcpf(dB6), sB0);
            sA1 = fmaf(w[k+7], __builtin_amdgcn_rcpf(dA7), sA1);
            sB1 = fmaf(w[k+7], __builtin_amdgcn_rcpf(dB7), sB1);
        }
        float sA = sA0 + sA1;
        float sB = sB0 + sB1;
        #pragma unroll
        for (int m = 1; m <= 8; m <<= 1) {
            sA += __shfl_xor(sA, m);
            sB += __shfl_xor(sB, m);
        }
        if (nl == 0) {
            const int v = wave * 32 + pass * 4 + vl;
            e_s[0][v] = fmaf(-2.f, sA, sumw);
            e_s[1][v] = fmaf(-2.f, sB, sumw);
        }
    }
    __syncthreads();

    // softmax: wave 0 -> q0, wave 1 -> q1
    if (wave < 2) {
        float e0 = e_s[wave][lane];
        float e1 = e_s[wave][lane + 64];
        float m = fmaxf(e0, e1);
        #pragma unroll
        for (int off = 32; off; off >>= 1) m = fmaxf(m, __shfl_xor(m, off));
        float x0 = __builtin_amdgcn_exp2f((e0 - m) * LOG2E);
        float x1 = __builtin_amdgcn_exp2f((e1 - m) * LOG2E);
        float ss = x0 + x1;
        #pragma unroll
        for (int off = 32; off; off >>= 1) ss += __shfl_xor(ss, off);
        float inv = __builtin_amdgcn_rcpf(ss);
        float p0 = x0 * inv, p1 = x1 * inv;
        size_t o = (size_t)(row0 + wave) * NLV;
        out_w[o + lane]      = p0;
        out_w[o + lane + 64] = p1;
        out_e[o + lane]      = e0;
        out_e[o + lane + 64] = e1;
    }
}

// ---------------- aligned (bf16 vis; p read from out_w) ---------------------
// blk = qg*32 + b (qg: group of 4 q). Thread owns 4 f for 4 q.
__global__ __launch_bounds__(256) void aligned_k(
    const us* __restrict__ vis_b,     // [32,128,1024] bf16
    const float* __restrict__ p_w,    // [2048,128] fp32 (= out_w)
    float* __restrict__ out_sgf)      // [32,64,1536]
{
    const int blk = blockIdx.x;
    const int b   = blk & 31;
    const int qg  = blk >> 5;         // 0..15
    const int tid = threadIdx.x;

    __shared__ float p_s[4][128];
    if (tid < 128) {
        const float* src = p_w + (size_t)(b * NLQ + qg * 4) * NLV;
        ((float4*)&p_s[0][0])[tid] = ((const float4*)src)[tid];
    }
    __syncthreads();

    const int f0 = tid * 4;
    float4 acc[4] = {};
    const us* vb = vis_b + (size_t)b * NLV * NFS + f0;
    for (int v0 = 0; v0 < NLV; v0 += 4) {
        float4 pv[4];
        #pragma unroll
        for (int qq = 0; qq < 4; ++qq) pv[qq] = *(const float4*)&p_s[qq][v0];
        #pragma unroll
        for (int dv = 0; dv < 4; ++dv) {
            uint2 u = *(const uint2*)(vb + (size_t)(v0 + dv) * NFS);
            float x0 = blo(u.x), x1 = bhi(u.x), x2 = blo(u.y), x3 = bhi(u.y);
            #pragma unroll
            for (int qq = 0; qq < 4; ++qq) {
                float p = (dv == 0) ? pv[qq].x : (dv == 1) ? pv[qq].y
                        : (dv == 2) ? pv[qq].z : pv[qq].w;
                acc[qq].x = fmaf(p, x0, acc[qq].x);
                acc[qq].y = fmaf(p, x1, acc[qq].y);
                acc[qq].z = fmaf(p, x2, acc[qq].z);
                acc[qq].w = fmaf(p, x3, acc[qq].w);
            }
        }
    }
    #pragma unroll
    for (int qq = 0; qq < 4; ++qq) {
        size_t row = (size_t)(b * NLQ + qg * 4 + qq);
        *(float4*)(out_sgf + row * (NQS + NFS) + NQS + f0) = acc[qq];
    }
}

extern "C" void kernel_launch(void* const* d_in, const int* in_sizes, int n_in,
                              void* d_out, int out_size, void* d_ws, size_t ws_size,
                              hipStream_t stream) {
    const float* phr  = (const float*)d_in[0];
    const float* vis  = (const float*)d_in[1];
    const float* W    = (const float*)d_in[2];
    const float* U    = (const float*)d_in[3];
    const float* bias = (const float*)d_in[4];
    const float* wvec = (const float*)d_in[5];

    char* ws = (char*)d_ws;
    us* phr_b = (us*)ws;                                  // 2 MB
    us* vis_b = (us*)(ws + (2u << 20));                   // 8 MB
    us* W_b   = (us*)(ws + (10u << 20));                  // 0.5 MB
    us* U_b   = (us*)(ws + (10u << 20) + (512u << 10));   // 1 MB
    us* whY   = (us*)(ws + (12u << 20));                  // 2 MB
    us* uvY   = (us*)(ws + (14u << 20));                  // 4 MB

    float* out     = (float*)d_out;
    float* out_sgf = out;
    float* out_w   = out_sgf + (size_t)NB * NLQ * (NQS + NFS);
    float* out_e   = out_w   + (size_t)NB * NLQ * NLV;

    convert_bf16<<<(TOT4 + 255) / 256, 256, 0, stream>>>(
        phr, vis, W, U, phr_b, vis_b, W_b, U_b, out_sgf);
    gemm_both<<<768, 256, 0, stream>>>(phr_b, W_b, bias, vis_b, U_b, whY, uvY);
    energize<<<NB * NLQ / 2, 256, 0, stream>>>(whY, uvY, wvec, out_w, out_e);
    aligned_k<<<NB * 16, 256, 0, stream>>>(vis_b, out_w, out_sgf);
}